// Round 4
// baseline (288.481 us; speedup 1.0000x reference)
//
#include <hip/hip_runtime.h>
#include <hip/hip_bf16.h>

// ---------------------------------------------------------------------------
// Problem constants
// ---------------------------------------------------------------------------
#define BATCH 2
#define CCH   512          // input channels
#define NSEQ  2048         // sequence length
#define HEADS 16
#define DHEAD 64
#define HDIM  1024         // HEADS*DHEAD
#define ODIM  3072         // 3*HDIM
#define SCALE 8.0f

typedef short short8 __attribute__((ext_vector_type(8)));
typedef float float4v __attribute__((ext_vector_type(4)));

__device__ __forceinline__ float bf2f(unsigned short b) {
    return __uint_as_float(((unsigned int)b) << 16);
}
__device__ __forceinline__ unsigned short f2bf(float f) {
    unsigned int u = __float_as_uint(f);
    unsigned int r = (u + 0x7FFFu + ((u >> 16) & 1u)) >> 16;
    return (unsigned short)r;
}

// async global->LDS, 16B per lane (wave-uniform LDS base + lane*16)
typedef __attribute__((address_space(1))) const void* as1_cvp;
typedef __attribute__((address_space(3))) void* as3_vp;
__device__ __forceinline__ void cp16(const void* g, void* l) {
    __builtin_amdgcn_global_load_lds((as1_cvp)g, (as3_vp)l, 16, 0, 0);
}

// ---------------------------------------------------------------------------
// Kernel S: sniff input dtype (flag=1 -> inputs are f32).
// ---------------------------------------------------------------------------
__global__ __launch_bounds__(64) void k_sniff(const unsigned short* __restrict__ w,
                                              int* __restrict__ flag) {
    int lane = threadIdx.x;
    int cnt = 0;
#pragma unroll
    for (int s = 0; s < 4; ++s) {
        unsigned short u = w[lane + s * 64];
        int e = (u >> 7) & 0xFF;
        if (e >= 128) cnt++;
    }
#pragma unroll
    for (int off = 1; off < 64; off <<= 1) cnt += __shfl_xor(cnt, off);
    if (lane == 0) *flag = (cnt > 8) ? 1 : 0;
}

// ---------------------------------------------------------------------------
// Kernel C: dtype-normalizing copy: src (f32 or bf16 per flag) -> bf16 dst
// ---------------------------------------------------------------------------
__global__ __launch_bounds__(256) void k_convert(const void* __restrict__ src,
                                                 unsigned short* __restrict__ dst,
                                                 int n, const int* __restrict__ flag) {
    int i = blockIdx.x * 256 + threadIdx.x;
    if (i >= n) return;
    if (*flag) dst[i] = f2bf(((const float*)src)[i]);
    else       dst[i] = ((const unsigned short*)src)[i];
}

// ---------------------------------------------------------------------------
// Kernel 0: transpose x [b][c][n] -> xt [b][n][c] (bf16), dtype-flexible load
// ---------------------------------------------------------------------------
__global__ __launch_bounds__(256) void k_transpose_x(
    const void* __restrict__ x, unsigned short* __restrict__ xt,
    const int* __restrict__ flag) {
    __shared__ unsigned short t[64][65];
    const int fl = *flag;
    const int b  = blockIdx.z;
    const int c0 = blockIdx.y * 64;
    const int n0 = blockIdx.x * 64;
    const int tr = threadIdx.x >> 6;   // 0..3
    const int tc = threadIdx.x & 63;
    const unsigned short* xu = (const unsigned short*)x + (size_t)b * CCH * NSEQ;
    const float*          xf = (const float*)x          + (size_t)b * CCH * NSEQ;
    unsigned short* xd = xt + (size_t)b * NSEQ * CCH;
#pragma unroll
    for (int r = 0; r < 16; ++r) {
        int c = r * 4 + tr;
        size_t idx = (size_t)(c0 + c) * NSEQ + n0 + tc;
        t[c][tc] = fl ? f2bf(xf[idx]) : xu[idx];
    }
    __syncthreads();
#pragma unroll
    for (int r = 0; r < 16; ++r) {
        int n = r * 4 + tr;
        xd[(size_t)(n0 + n) * CCH + c0 + tc] = t[tc][n];
    }
}

// ---------------------------------------------------------------------------
// Kernel 1: QKV GEMM (m97 pattern).
// qkv[b][o][n] (f32) = sum_c Wqkv[o][c] * xt[b][n][c]
// ---------------------------------------------------------------------------
__global__ __launch_bounds__(256) void k_gemm_qkv(
    const unsigned short* __restrict__ W,   // [3072][512] bf16 (converted)
    const unsigned short* __restrict__ xt,  // [b][2048][512] bf16
    float* __restrict__ out) {              // [b][3072][2048] f32
    constexpr int K = CCH, N = NSEQ, M = ODIM;
    __shared__ __align__(16) short lsA[128 * 64];
    __shared__ __align__(16) short lsB[128 * 64];
    const int tid = threadIdx.x, wave = tid >> 6, lane = tid & 63;
    const int l15 = lane & 15, quad = lane >> 4, q8 = quad * 8;
    const int n0 = blockIdx.x * 128, m0 = blockIdx.y * 128, z = blockIdx.z;
    const short* Ab = (const short*)W + (size_t)m0 * K;
    const short* Bb = (const short*)xt + ((size_t)z * N + n0) * K;
    const int wm = wave >> 1, wn = wave & 1;

    float4v acc[4][4];
#pragma unroll
    for (int i = 0; i < 4; ++i)
#pragma unroll
        for (int j = 0; j < 4; ++j) acc[i][j] = (float4v){0.f, 0.f, 0.f, 0.f};

    for (int k0 = 0; k0 < K; k0 += 64) {
#pragma unroll
        for (int it = 0; it < 4; ++it) {
            int flat = it * 2048 + tid * 8;
            int row = flat >> 6, col = flat & 63;
            cp16(Ab + (size_t)row * K + k0 + col, &lsA[it * 2048 + wave * 512]);
            cp16(Bb + (size_t)row * K + k0 + col, &lsB[it * 2048 + wave * 512]);
        }
        __syncthreads();
        short8 af[4][2], bfr[4][2];
#pragma unroll
        for (int t = 0; t < 4; ++t)
#pragma unroll
            for (int kk = 0; kk < 2; ++kk) {
                af[t][kk]  = *(const short8*)&lsA[(wm * 64 + t * 16 + l15) * 64 + kk * 32 + q8];
                bfr[t][kk] = *(const short8*)&lsB[(wn * 64 + t * 16 + l15) * 64 + kk * 32 + q8];
            }
#pragma unroll
        for (int mt = 0; mt < 4; ++mt)
#pragma unroll
            for (int nt = 0; nt < 4; ++nt) {
                acc[mt][nt] = __builtin_amdgcn_mfma_f32_16x16x32_bf16(af[mt][0], bfr[nt][0], acc[mt][nt], 0, 0, 0);
                acc[mt][nt] = __builtin_amdgcn_mfma_f32_16x16x32_bf16(af[mt][1], bfr[nt][1], acc[mt][nt], 0, 0, 0);
            }
        __syncthreads();
    }
    float* Co = out + (size_t)z * M * N;
#pragma unroll
    for (int mt = 0; mt < 4; ++mt)
#pragma unroll
        for (int nt = 0; nt < 4; ++nt)
#pragma unroll
            for (int r = 0; r < 4; ++r) {
                int mr = m0 + wm * 64 + mt * 16 + quad * 4 + r;
                int nc = n0 + wn * 64 + nt * 16 + l15;
                Co[(size_t)mr * N + nc] = acc[mt][nt][r];
            }
}

// ---------------------------------------------------------------------------
// Kernel 2: repack+normalize q,k -> qh/kh bf16 [b*H+h][n][d]
// ---------------------------------------------------------------------------
__global__ __launch_bounds__(256) void k_repack_qk(
    const float* __restrict__ qkv,
    const unsigned short* __restrict__ qs, const unsigned short* __restrict__ ks,
    unsigned short* __restrict__ qh, unsigned short* __restrict__ kh) {
    __shared__ float tile[64][65];
    __shared__ float ps[4][64];
    __shared__ float inv[64];
    const int n0 = blockIdx.x * 64;
    const int bh = blockIdx.y, b = bh >> 4, h = bh & 15;
    const int isK = blockIdx.z;
    const int tr = threadIdx.x >> 6, tc = threadIdx.x & 63;
    const float* src = qkv + ((size_t)b * ODIM + (size_t)isK * HDIM + h * DHEAD) * NSEQ;
#pragma unroll
    for (int r = 0; r < 16; ++r) {
        int d = r * 4 + tr;
        tile[d][tc] = src[(size_t)d * NSEQ + n0 + tc];
    }
    __syncthreads();
    {
        float s = 0.f;
#pragma unroll
        for (int d = 0; d < 16; ++d) {
            float v = tile[tr * 16 + d][tc];
            s += v * v;
        }
        ps[tr][tc] = s;
    }
    __syncthreads();
    if (threadIdx.x < 64) {
        float s = ps[0][threadIdx.x] + ps[1][threadIdx.x] + ps[2][threadIdx.x] + ps[3][threadIdx.x];
        inv[threadIdx.x] = 1.0f / fmaxf(sqrtf(s), 1e-12f);
    }
    __syncthreads();
    const unsigned short* sc = isK ? ks : qs;
    unsigned short* dst = (isK ? kh : qh) + (size_t)bh * NSEQ * DHEAD;
    const float scd = bf2f(sc[tc]);   // d = tc in the write phase
#pragma unroll
    for (int r = 0; r < 16; ++r) {
        int n = r * 4 + tr;
        float v = tile[tc][n] * inv[n] * scd;
        dst[(size_t)(n0 + n) * DHEAD + tc] = f2bf(v);
    }
}

// ---------------------------------------------------------------------------
// Kernel 3: cast v part of qkv (f32) to bf16, layout kept [b*H+h][d][n]
// ---------------------------------------------------------------------------
__global__ __launch_bounds__(256) void k_vcast(
    const float* __restrict__ qkv, unsigned short* __restrict__ vb) {
    size_t i = ((size_t)blockIdx.x * 256 + threadIdx.x) * 4;  // over B*HDIM*NSEQ
    size_t b = i >> 21;                      // HDIM*NSEQ = 2^21
    size_t rem = i & ((1u << 21) - 1);
    const float4* src = (const float4*)(qkv + b * ((size_t)ODIM * NSEQ) + (size_t)2 * HDIM * NSEQ + rem);
    float4 v = *src;
    ushort4 o;
    o.x = f2bf(v.x); o.y = f2bf(v.y); o.z = f2bf(v.z); o.w = f2bf(v.w);
    *(ushort4*)(vb + i) = o;
}

// ---------------------------------------------------------------------------
// Kernel 4: flash attention per (b,h).  128 q-rows per block, j-tiles of 64.
// ---------------------------------------------------------------------------
__global__ __launch_bounds__(256) void k_attn(
    const unsigned short* __restrict__ qh, const unsigned short* __restrict__ kh,
    const unsigned short* __restrict__ vb, unsigned short* __restrict__ aot) {
    __shared__ __align__(16) short Kt[64 * 64];
    __shared__ __align__(16) short Vt[64 * 64];
    __shared__ __align__(16) short Pt[128 * 64];
    const int tid = threadIdx.x, wave = tid >> 6, lane = tid & 63;
    const int l15 = lane & 15, quad = lane >> 4, q8 = quad * 8;
    const int i0 = blockIdx.x * 128;
    const int bh = blockIdx.y, b = bh >> 4, h = bh & 15;

    short8 qf[2][2];
    const short* qb = (const short*)qh + ((size_t)bh * NSEQ + i0 + wave * 32) * DHEAD;
#pragma unroll
    for (int mt = 0; mt < 2; ++mt)
#pragma unroll
        for (int kt = 0; kt < 2; ++kt)
            qf[mt][kt] = *(const short8*)&qb[(mt * 16 + l15) * DHEAD + kt * 32 + q8];

    float4v of[2][4];
#pragma unroll
    for (int mt = 0; mt < 2; ++mt)
#pragma unroll
        for (int dt = 0; dt < 4; ++dt) of[mt][dt] = (float4v){0.f, 0.f, 0.f, 0.f};
    float m_st[2][4], l_st[2][4];
#pragma unroll
    for (int mt = 0; mt < 2; ++mt)
#pragma unroll
        for (int r = 0; r < 4; ++r) { m_st[mt][r] = -INFINITY; l_st[mt][r] = 0.f; }

    const short* kbase = (const short*)kh + (size_t)bh * NSEQ * DHEAD;
    const short* vbase = (const short*)vb + (size_t)bh * DHEAD * NSEQ;

    for (int j0 = 0; j0 < NSEQ; j0 += 64) {
#pragma unroll
        for (int it = 0; it < 2; ++it) {
            int flat = it * 2048 + tid * 8;
            int row = flat >> 6, col = flat & 63;
            cp16(kbase + (size_t)(j0 + row) * DHEAD + col, &Kt[it * 2048 + wave * 512]);
            cp16(vbase + (size_t)row * NSEQ + j0 + col, &Vt[it * 2048 + wave * 512]);
        }
        __syncthreads();

        short8 kf[4][2];
#pragma unroll
        for (int nt = 0; nt < 4; ++nt)
#pragma unroll
            for (int kt = 0; kt < 2; ++kt)
                kf[nt][kt] = *(const short8*)&Kt[(nt * 16 + l15) * 64 + kt * 32 + q8];
        float4v s[2][4];
#pragma unroll
        for (int mt = 0; mt < 2; ++mt)
#pragma unroll
            for (int nt = 0; nt < 4; ++nt) {
                float4v z = (float4v){0.f, 0.f, 0.f, 0.f};
                z = __builtin_amdgcn_mfma_f32_16x16x32_bf16(qf[mt][0], kf[nt][0], z, 0, 0, 0);
                z = __builtin_amdgcn_mfma_f32_16x16x32_bf16(qf[mt][1], kf[nt][1], z, 0, 0, 0);
                s[mt][nt] = z;
            }

#pragma unroll
        for (int mt = 0; mt < 2; ++mt)
#pragma unroll
            for (int r = 0; r < 4; ++r) {
                float mx = s[mt][0][r];
#pragma unroll
                for (int nt = 1; nt < 4; ++nt) mx = fmaxf(mx, s[mt][nt][r]);
                mx *= SCALE;
#pragma unroll
                for (int off = 1; off < 16; off <<= 1) mx = fmaxf(mx, __shfl_xor(mx, off));
                float mnew = fmaxf(m_st[mt][r], mx);
                float alpha = __expf(m_st[mt][r] - mnew);
                m_st[mt][r] = mnew;
                float rs = 0.f;
#pragma unroll
                for (int nt = 0; nt < 4; ++nt) {
                    float p = __expf(s[mt][nt][r] * SCALE - mnew);
                    rs += p;
                    Pt[(wave * 32 + mt * 16 + quad * 4 + r) * 64 + nt * 16 + l15] = (short)f2bf(p);
                }
#pragma unroll
                for (int off = 1; off < 16; off <<= 1) rs += __shfl_xor(rs, off);
                l_st[mt][r] = l_st[mt][r] * alpha + rs;
#pragma unroll
                for (int dt = 0; dt < 4; ++dt) of[mt][dt][r] *= alpha;
            }
        __syncthreads();

        short8 vf[4][2];
#pragma unroll
        for (int dt = 0; dt < 4; ++dt)
#pragma unroll
            for (int kt = 0; kt < 2; ++kt)
                vf[dt][kt] = *(const short8*)&Vt[(dt * 16 + l15) * 64 + kt * 32 + q8];
#pragma unroll
        for (int mt = 0; mt < 2; ++mt) {
            short8 af0 = *(const short8*)&Pt[(wave * 32 + mt * 16 + l15) * 64 + q8];
            short8 af1 = *(const short8*)&Pt[(wave * 32 + mt * 16 + l15) * 64 + 32 + q8];
#pragma unroll
            for (int dt = 0; dt < 4; ++dt) {
                of[mt][dt] = __builtin_amdgcn_mfma_f32_16x16x32_bf16(af0, vf[dt][0], of[mt][dt], 0, 0, 0);
                of[mt][dt] = __builtin_amdgcn_mfma_f32_16x16x32_bf16(af1, vf[dt][1], of[mt][dt], 0, 0, 0);
            }
        }
        __syncthreads();
    }

    unsigned short* outb = aot + (size_t)b * NSEQ * HDIM;
#pragma unroll
    for (int mt = 0; mt < 2; ++mt)
#pragma unroll
        for (int dt = 0; dt < 4; ++dt)
#pragma unroll
            for (int r = 0; r < 4; ++r) {
                float v = of[mt][dt][r] / l_st[mt][r];
                int i = i0 + wave * 32 + mt * 16 + quad * 4 + r;
                int c = h * DHEAD + dt * 16 + l15;
                outb[(size_t)i * HDIM + c] = f2bf(v);
            }
}

// ---------------------------------------------------------------------------
// Kernel 5: output GEMM. y[b][o][n] = sum_c Wout[o][c]*aot[b][n][c] + bout[o]
// OUTPUT IS f32 (reference dtype).
// ---------------------------------------------------------------------------
__global__ __launch_bounds__(256) void k_gemm_out(
    const unsigned short* __restrict__ W,    // [512][1024] bf16 (converted)
    const unsigned short* __restrict__ aot,  // [b][2048][1024] bf16
    const unsigned short* __restrict__ bias, // [512] bf16 (converted)
    float* __restrict__ out) {               // [b][512][2048] f32
    constexpr int K = HDIM, N = NSEQ, M = CCH;
    __shared__ __align__(16) short lsA[128 * 64];
    __shared__ __align__(16) short lsB[128 * 64];
    const int tid = threadIdx.x, wave = tid >> 6, lane = tid & 63;
    const int l15 = lane & 15, quad = lane >> 4, q8 = quad * 8;
    const int n0 = blockIdx.x * 128, m0 = blockIdx.y * 128, z = blockIdx.z;
    const short* Ab = (const short*)W + (size_t)m0 * K;
    const short* Bb = (const short*)aot + ((size_t)z * N + n0) * K;
    const int wm = wave >> 1, wn = wave & 1;

    float4v acc[4][4];
#pragma unroll
    for (int i = 0; i < 4; ++i)
#pragma unroll
        for (int j = 0; j < 4; ++j) acc[i][j] = (float4v){0.f, 0.f, 0.f, 0.f};

    for (int k0 = 0; k0 < K; k0 += 64) {
#pragma unroll
        for (int it = 0; it < 4; ++it) {
            int flat = it * 2048 + tid * 8;
            int row = flat >> 6, col = flat & 63;
            cp16(Ab + (size_t)row * K + k0 + col, &lsA[it * 2048 + wave * 512]);
            cp16(Bb + (size_t)row * K + k0 + col, &lsB[it * 2048 + wave * 512]);
        }
        __syncthreads();
        short8 af[4][2], bfr[4][2];
#pragma unroll
        for (int t = 0; t < 4; ++t)
#pragma unroll
            for (int kk = 0; kk < 2; ++kk) {
                af[t][kk]  = *(const short8*)&lsA[(wm * 64 + t * 16 + l15) * 64 + kk * 32 + q8];
                bfr[t][kk] = *(const short8*)&lsB[(wn * 64 + t * 16 + l15) * 64 + kk * 32 + q8];
            }
#pragma unroll
        for (int mt = 0; mt < 4; ++mt)
#pragma unroll
            for (int nt = 0; nt < 4; ++nt) {
                acc[mt][nt] = __builtin_amdgcn_mfma_f32_16x16x32_bf16(af[mt][0], bfr[nt][0], acc[mt][nt], 0, 0, 0);
                acc[mt][nt] = __builtin_amdgcn_mfma_f32_16x16x32_bf16(af[mt][1], bfr[nt][1], acc[mt][nt], 0, 0, 0);
            }
        __syncthreads();
    }
    float* Co = out + (size_t)z * M * N;
#pragma unroll
    for (int mt = 0; mt < 4; ++mt)
#pragma unroll
        for (int nt = 0; nt < 4; ++nt) {
            int mrow = m0 + wm * 64 + mt * 16 + quad * 4;
#pragma unroll
            for (int r = 0; r < 4; ++r) {
                int mr = mrow + r;
                int nc = n0 + wn * 64 + nt * 16 + l15;
                Co[(size_t)mr * N + nc] = acc[mt][nt][r] + bf2f(bias[mr]);
            }
        }
}

// ---------------------------------------------------------------------------
// Launch.  Inputs resolved BY SIZE (robust to ordering):
//   x=2097152, Wqkv=1572864, Wout=524288, bout=512, q_scale/k_scale=64 (in order)
// ---------------------------------------------------------------------------
extern "C" void kernel_launch(void* const* d_in, const int* in_sizes, int n_in,
                              void* d_out, int out_size, void* d_ws, size_t ws_size,
                              hipStream_t stream) {
    const void* x_raw    = nullptr;
    const void* Wqkv_raw = nullptr;
    const void* qs_raw   = nullptr;
    const void* ks_raw   = nullptr;
    const void* Wout_raw = nullptr;
    const void* bout_raw = nullptr;
    for (int i = 0; i < n_in; ++i) {
        switch (in_sizes[i]) {
            case BATCH * CCH * NSEQ: x_raw    = d_in[i]; break;   // 2,097,152
            case ODIM * CCH:         Wqkv_raw = d_in[i]; break;   // 1,572,864
            case CCH * HDIM:         Wout_raw = d_in[i]; break;   //   524,288
            case CCH:                bout_raw = d_in[i]; break;   //       512
            case DHEAD:                                            //        64
                if (!qs_raw) qs_raw = d_in[i]; else ks_raw = d_in[i];
                break;
            default: break;
        }
    }
    float* y = (float*)d_out;

    char* ws = (char*)d_ws;
    // ws layout (byte offsets)
    int*            flag  = (int*)(ws + 0);
    unsigned short* qsb   = (unsigned short*)(ws + 256);
    unsigned short* ksb   = (unsigned short*)(ws + 512);
    unsigned short* boutb = (unsigned short*)(ws + 768);
    unsigned short* Wqkvb = (unsigned short*)(ws + 4096);        // 3,145,728 B
    unsigned short* Woutb = (unsigned short*)(ws + 3149824);     // 1,048,576 B
    unsigned short* xt    = (unsigned short*)(ws + 4198400);     // 4,194,304 B
    float*          qkv   = (float*)(ws + 8392704);              // 50,331,648 B
    unsigned short* qh    = (unsigned short*)(ws + 58724352);    // 8,388,608 B
    unsigned short* kh    = (unsigned short*)(ws + 67112960);    // 8,388,608 B
    unsigned short* vb    = (unsigned short*)(ws + 75501568);    // 8,388,608 B
    unsigned short* aot   = (unsigned short*)(ws + 83890176);    // 8,388,608 B -> 92,278,784 total

    k_sniff<<<1, 64, 0, stream>>>((const unsigned short*)Wqkv_raw, flag);
    k_convert<<<(ODIM * CCH + 255) / 256, 256, 0, stream>>>(Wqkv_raw, Wqkvb, ODIM * CCH, flag);
    k_convert<<<(CCH * HDIM + 255) / 256, 256, 0, stream>>>(Wout_raw, Woutb, CCH * HDIM, flag);
    k_convert<<<2, 256, 0, stream>>>(bout_raw, boutb, CCH, flag);
    k_convert<<<1, 256, 0, stream>>>(qs_raw, qsb, DHEAD, flag);
    k_convert<<<1, 256, 0, stream>>>(ks_raw, ksb, DHEAD, flag);

    k_transpose_x<<<dim3(NSEQ / 64, CCH / 64, BATCH), 256, 0, stream>>>(x_raw, xt, flag);
    k_gemm_qkv<<<dim3(NSEQ / 128, ODIM / 128, BATCH), 256, 0, stream>>>(Wqkvb, xt, qkv);
    k_repack_qk<<<dim3(NSEQ / 64, BATCH * HEADS, 2), 256, 0, stream>>>(qkv, qsb, ksb, qh, kh);
    k_vcast<<<dim3((BATCH * HDIM * NSEQ / 4) / 256), 256, 0, stream>>>(qkv, vb);
    k_attn<<<dim3(NSEQ / 128, BATCH * HEADS), 256, 0, stream>>>(qh, kh, vb, aot);
    k_gemm_out<<<dim3(NSEQ / 128, CCH / 128, BATCH), 256, 0, stream>>>(Woutb, aot, boutb, y);
}

// Round 5
// 195.699 us; speedup vs baseline: 1.4741x; 1.4741x over previous
//
#include <hip/hip_runtime.h>
#include <hip/hip_bf16.h>

// ---------------------------------------------------------------------------
// Problem constants.  Inputs are f32 (proven R1->R2), output f32 (proven R4).
// ---------------------------------------------------------------------------
#define BATCH 2
#define CCH   512
#define NSEQ  2048
#define HEADS 16
#define DHEAD 64
#define HDIM  1024
#define ODIM  3072
#define SCALE 8.0f

typedef short short8 __attribute__((ext_vector_type(8)));
typedef float float4v __attribute__((ext_vector_type(4)));

__device__ __forceinline__ float bf2f(unsigned short b) {
    return __uint_as_float(((unsigned int)b) << 16);
}
__device__ __forceinline__ unsigned short f2bf(float f) {
    unsigned int u = __float_as_uint(f);
    return (unsigned short)((u + 0x7FFFu + ((u >> 16) & 1u)) >> 16);
}

// async global->LDS, 16B/lane (LDS dest = wave base + lane*16)
typedef __attribute__((address_space(1))) const void* as1_cvp;
typedef __attribute__((address_space(3))) void* as3_vp;
__device__ __forceinline__ void cp16(const void* g, void* l) {
    __builtin_amdgcn_global_load_lds((as1_cvp)g, (as3_vp)l, 16, 0, 0);
}
// LDS XOR swizzle: slot (row, chunk) holds global (row, chunk ^ (row&7)).
// Staging lane fetches global chunk (tid&7)^((tid>>3)&7); reader of global
// chunk c in row r reads LDS chunk c^(r&7).  Breaks the 128B-stride 16-way
// bank conflict on ds_read_b128 down to 2-way (free).

// ---------------------------------------------------------------------------
// k_prep: M = SCALE * max_d |qs_d * ks_d|  (softmax upper bound, exact since
// q,k rows are l2-normalized: |q.k| <= max|qs*ks| by Cauchy-Schwarz)
// ---------------------------------------------------------------------------
__global__ __launch_bounds__(64) void k_prep(const float* __restrict__ qs,
                                             const float* __restrict__ ks,
                                             float* __restrict__ M) {
    int lane = threadIdx.x;
    float p = fabsf(qs[lane] * ks[lane]);
#pragma unroll
    for (int off = 1; off < 64; off <<= 1) p = fmaxf(p, __shfl_xor(p, off));
    if (lane == 0) *M = SCALE * p;
}

// ---------------------------------------------------------------------------
// k_convert_w: f32 -> bf16 for Wqkv (1572864) then Wout (524288), 4/thread
// ---------------------------------------------------------------------------
__global__ __launch_bounds__(256) void k_convert_w(
    const float* __restrict__ Wqkv, const float* __restrict__ Wout,
    unsigned short* __restrict__ Wqkvb, unsigned short* __restrict__ Woutb) {
    int i4 = (blockIdx.x * 256 + threadIdx.x) * 4;
    const float* src; unsigned short* dst; int idx;
    if (i4 < ODIM * CCH) { src = Wqkv; dst = Wqkvb; idx = i4; }
    else { src = Wout; dst = Woutb; idx = i4 - ODIM * CCH; }
    float4 v = *(const float4*)(src + idx);
    ushort4 o;
    o.x = f2bf(v.x); o.y = f2bf(v.y); o.z = f2bf(v.z); o.w = f2bf(v.w);
    *(ushort4*)(dst + idx) = o;
}

// ---------------------------------------------------------------------------
// k_transpose_x: x [b][c][n] f32 -> xt [b][n][c] bf16
// ---------------------------------------------------------------------------
__global__ __launch_bounds__(256) void k_transpose_x(
    const float* __restrict__ x, unsigned short* __restrict__ xt) {
    __shared__ unsigned short t[64][65];
    const int b = blockIdx.z, c0 = blockIdx.y * 64, n0 = blockIdx.x * 64;
    const int tr = threadIdx.x >> 6, tc = threadIdx.x & 63;
    const float* xs = x + (size_t)b * CCH * NSEQ;
    unsigned short* xd = xt + (size_t)b * NSEQ * CCH;
#pragma unroll
    for (int r = 0; r < 16; ++r) {
        int c = r * 4 + tr;
        t[c][tc] = f2bf(xs[(size_t)(c0 + c) * NSEQ + n0 + tc]);
    }
    __syncthreads();
#pragma unroll
    for (int r = 0; r < 16; ++r) {
        int n = r * 4 + tr;
        xd[(size_t)(n0 + n) * CCH + c0 + tc] = t[tc][n];
    }
}

// ---------------------------------------------------------------------------
// k_gemm_qkv: qkv[b][o][n] f32 = sum_c Wqkv[o][c]*xt[b][n][c]; 128x128, BK=64
// ---------------------------------------------------------------------------
__global__ __launch_bounds__(256) void k_gemm_qkv(
    const unsigned short* __restrict__ W, const unsigned short* __restrict__ xt,
    float* __restrict__ out) {
    constexpr int K = CCH, N = NSEQ, M = ODIM;
    __shared__ __align__(16) short lsA[128 * 64];
    __shared__ __align__(16) short lsB[128 * 64];
    const int tid = threadIdx.x, wave = tid >> 6, lane = tid & 63;
    const int l15 = lane & 15, quad = lane >> 4;
    const int n0 = blockIdx.x * 128, m0 = blockIdx.y * 128, z = blockIdx.z;
    const short* Ab = (const short*)W + (size_t)m0 * K;
    const short* Bb = (const short*)xt + ((size_t)z * N + n0) * K;
    const int wm = wave >> 1, wn = wave & 1;
    const int cswz = (((tid & 7) ^ ((tid >> 3) & 7))) * 8;   // swizzled global col
    const int sw7 = (l15 & 7);

    float4v acc[4][4];
#pragma unroll
    for (int i = 0; i < 4; ++i)
#pragma unroll
        for (int j = 0; j < 4; ++j) acc[i][j] = (float4v){0.f, 0.f, 0.f, 0.f};

    for (int k0 = 0; k0 < K; k0 += 64) {
#pragma unroll
        for (int it = 0; it < 4; ++it) {
            int row = it * 32 + (tid >> 3);
            cp16(Ab + (size_t)row * K + k0 + cswz, &lsA[it * 2048 + wave * 512]);
            cp16(Bb + (size_t)row * K + k0 + cswz, &lsB[it * 2048 + wave * 512]);
        }
        __syncthreads();
        short8 af[4][2], bfr[4][2];
#pragma unroll
        for (int t = 0; t < 4; ++t)
#pragma unroll
            for (int kk = 0; kk < 2; ++kk) {
                af[t][kk]  = *(const short8*)&lsA[(wm * 64 + t * 16 + l15) * 64 + ((kk * 4 + quad) ^ sw7) * 8];
                bfr[t][kk] = *(const short8*)&lsB[(wn * 64 + t * 16 + l15) * 64 + ((kk * 4 + quad) ^ sw7) * 8];
            }
#pragma unroll
        for (int mt = 0; mt < 4; ++mt)
#pragma unroll
            for (int nt = 0; nt < 4; ++nt) {
                acc[mt][nt] = __builtin_amdgcn_mfma_f32_16x16x32_bf16(af[mt][0], bfr[nt][0], acc[mt][nt], 0, 0, 0);
                acc[mt][nt] = __builtin_amdgcn_mfma_f32_16x16x32_bf16(af[mt][1], bfr[nt][1], acc[mt][nt], 0, 0, 0);
            }
        __syncthreads();
    }
    float* Co = out + (size_t)z * M * N;
#pragma unroll
    for (int mt = 0; mt < 4; ++mt)
#pragma unroll
        for (int nt = 0; nt < 4; ++nt)
#pragma unroll
            for (int r = 0; r < 4; ++r) {
                int mr = m0 + wm * 64 + mt * 16 + quad * 4 + r;
                int nc = n0 + wn * 64 + nt * 16 + l15;
                Co[(size_t)mr * N + nc] = acc[mt][nt][r];
            }
}

// ---------------------------------------------------------------------------
// k_repack_qk: l2-norm + scale -> qh/kh bf16 [bh][n][d]
// ---------------------------------------------------------------------------
__global__ __launch_bounds__(256) void k_repack_qk(
    const float* __restrict__ qkv,
    const float* __restrict__ qs, const float* __restrict__ ks,
    unsigned short* __restrict__ qh, unsigned short* __restrict__ kh) {
    __shared__ float tile[64][65];
    __shared__ float ps[4][64];
    __shared__ float inv[64];
    const int n0 = blockIdx.x * 64;
    const int bh = blockIdx.y, b = bh >> 4, h = bh & 15;
    const int isK = blockIdx.z;
    const int tr = threadIdx.x >> 6, tc = threadIdx.x & 63;
    const float* src = qkv + ((size_t)b * ODIM + (size_t)isK * HDIM + h * DHEAD) * NSEQ;
#pragma unroll
    for (int r = 0; r < 16; ++r) {
        int d = r * 4 + tr;
        tile[d][tc] = src[(size_t)d * NSEQ + n0 + tc];
    }
    __syncthreads();
    {
        float s = 0.f;
#pragma unroll
        for (int d = 0; d < 16; ++d) { float v = tile[tr * 16 + d][tc]; s += v * v; }
        ps[tr][tc] = s;
    }
    __syncthreads();
    if (threadIdx.x < 64) {
        float s = ps[0][threadIdx.x] + ps[1][threadIdx.x] + ps[2][threadIdx.x] + ps[3][threadIdx.x];
        inv[threadIdx.x] = 1.0f / fmaxf(sqrtf(s), 1e-12f);
    }
    __syncthreads();
    const float* sc = isK ? ks : qs;
    unsigned short* dst = (isK ? kh : qh) + (size_t)bh * NSEQ * DHEAD;
    const float scd = sc[tc];
#pragma unroll
    for (int r = 0; r < 16; ++r) {
        int n = r * 4 + tr;
        dst[(size_t)(n0 + n) * DHEAD + tc] = f2bf(tile[tc][n] * inv[n] * scd);
    }
}

// ---------------------------------------------------------------------------
// k_vcast: v part of qkv f32 -> vb bf16, layout kept [bh][d][n]
// ---------------------------------------------------------------------------
__global__ __launch_bounds__(256) void k_vcast(
    const float* __restrict__ qkv, unsigned short* __restrict__ vb) {
    size_t i = ((size_t)blockIdx.x * 256 + threadIdx.x) * 4;
    size_t b = i >> 21;
    size_t rem = i & ((1u << 21) - 1);
    float4 v = *(const float4*)(qkv + b * ((size_t)ODIM * NSEQ) + (size_t)2 * HDIM * NSEQ + rem);
    ushort4 o;
    o.x = f2bf(v.x); o.y = f2bf(v.y); o.z = f2bf(v.z); o.w = f2bf(v.w);
    *(ushort4*)(vb + i) = o;
}

// ---------------------------------------------------------------------------
// k_attn: fixed-M flash attention, j-split in 2 (exact: no running max).
// 128 q-rows/block, j-tiles of 64, swizzled LDS.  Partials: opart f32, lpart.
// ---------------------------------------------------------------------------
__global__ __launch_bounds__(256, 4) void k_attn(
    const unsigned short* __restrict__ qh, const unsigned short* __restrict__ kh,
    const unsigned short* __restrict__ vb,
    float* __restrict__ opart, float* __restrict__ lpart,
    const float* __restrict__ Mptr) {
    __shared__ __align__(16) short Kt[64 * 64];
    __shared__ __align__(16) short Vt[64 * 64];
    __shared__ __align__(16) short Pt[128 * 64];
    const int tid = threadIdx.x, wave = tid >> 6, lane = tid & 63;
    const int l15 = lane & 15, quad = lane >> 4, q8 = quad * 8;
    const int i0 = blockIdx.x * 128;
    const int bh = blockIdx.y;
    const int z = blockIdx.z;
    const float Ms = *Mptr;
    const int cswz = (((tid & 7) ^ ((tid >> 3) & 7))) * 8;
    const int sw7 = (l15 & 7);

    short8 qf[2][2];
    const short* qb = (const short*)qh + ((size_t)bh * NSEQ + i0 + wave * 32) * DHEAD;
#pragma unroll
    for (int mt = 0; mt < 2; ++mt)
#pragma unroll
        for (int kt = 0; kt < 2; ++kt)
            qf[mt][kt] = *(const short8*)&qb[(mt * 16 + l15) * DHEAD + kt * 32 + q8];

    float4v of[2][4];
#pragma unroll
    for (int mt = 0; mt < 2; ++mt)
#pragma unroll
        for (int dt = 0; dt < 4; ++dt) of[mt][dt] = (float4v){0.f, 0.f, 0.f, 0.f};
    float l_acc[2][4];
#pragma unroll
    for (int mt = 0; mt < 2; ++mt)
#pragma unroll
        for (int r = 0; r < 4; ++r) l_acc[mt][r] = 0.f;

    const short* kbase = (const short*)kh + (size_t)bh * NSEQ * DHEAD;
    const short* vbase = (const short*)vb + (size_t)bh * DHEAD * NSEQ;

    const int jlo = z * (NSEQ / 2), jhi = jlo + NSEQ / 2;
    for (int j0 = jlo; j0 < jhi; j0 += 64) {
#pragma unroll
        for (int it = 0; it < 2; ++it) {
            int row = it * 32 + (tid >> 3);
            cp16(kbase + (size_t)(j0 + row) * DHEAD + cswz, &Kt[it * 2048 + wave * 512]);
            cp16(vbase + (size_t)row * NSEQ + j0 + cswz, &Vt[it * 2048 + wave * 512]);
        }
        __syncthreads();

        // S = Q K^T  (B-frag rows of Kt, swizzled chunks)
        float4v s[2][4];
#pragma unroll
        for (int nt = 0; nt < 4; ++nt) {
            short8 kf0 = *(const short8*)&Kt[(nt * 16 + l15) * 64 + ((0 * 4 + quad) ^ sw7) * 8];
            short8 kf1 = *(const short8*)&Kt[(nt * 16 + l15) * 64 + ((1 * 4 + quad) ^ sw7) * 8];
#pragma unroll
            for (int mt = 0; mt < 2; ++mt) {
                float4v zz = (float4v){0.f, 0.f, 0.f, 0.f};
                zz = __builtin_amdgcn_mfma_f32_16x16x32_bf16(qf[mt][0], kf0, zz, 0, 0, 0);
                zz = __builtin_amdgcn_mfma_f32_16x16x32_bf16(qf[mt][1], kf1, zz, 0, 0, 0);
                s[mt][nt] = zz;
            }
        }

        // fixed-M softmax: p = exp(8*s - M); no max tracking, no rescale
#pragma unroll
        for (int mt = 0; mt < 2; ++mt)
#pragma unroll
            for (int r = 0; r < 4; ++r) {
                int prow = wave * 32 + mt * 16 + quad * 4 + r;
                int psw = (prow & 7);
                float p0 = __expf(fmaf(s[mt][0][r], SCALE, -Ms));
                float p1 = __expf(fmaf(s[mt][1][r], SCALE, -Ms));
                float p2 = __expf(fmaf(s[mt][2][r], SCALE, -Ms));
                float p3 = __expf(fmaf(s[mt][3][r], SCALE, -Ms));
                l_acc[mt][r] += (p0 + p1) + (p2 + p3);
                // store swizzled: col = nt*16+l15 -> chunk (2nt + (l15>>3)) ^ (row&7)
                Pt[prow * 64 + (((0 * 2 + (l15 >> 3)) ^ psw) * 8) + (l15 & 7)] = (short)f2bf(p0);
                Pt[prow * 64 + (((1 * 2 + (l15 >> 3)) ^ psw) * 8) + (l15 & 7)] = (short)f2bf(p1);
                Pt[prow * 64 + (((2 * 2 + (l15 >> 3)) ^ psw) * 8) + (l15 & 7)] = (short)f2bf(p2);
                Pt[prow * 64 + (((3 * 2 + (l15 >> 3)) ^ psw) * 8) + (l15 & 7)] = (short)f2bf(p3);
            }
        __syncthreads();

        // O += P V
#pragma unroll
        for (int mt = 0; mt < 2; ++mt) {
            int arow = wave * 32 + mt * 16 + l15;
            short8 af0 = *(const short8*)&Pt[arow * 64 + ((0 * 4 + quad) ^ sw7) * 8];
            short8 af1 = *(const short8*)&Pt[arow * 64 + ((1 * 4 + quad) ^ sw7) * 8];
#pragma unroll
            for (int dt = 0; dt < 4; ++dt) {
                short8 vf0 = *(const short8*)&Vt[(dt * 16 + l15) * 64 + ((0 * 4 + quad) ^ sw7) * 8];
                short8 vf1 = *(const short8*)&Vt[(dt * 16 + l15) * 64 + ((1 * 4 + quad) ^ sw7) * 8];
                of[mt][dt] = __builtin_amdgcn_mfma_f32_16x16x32_bf16(af0, vf0, of[mt][dt], 0, 0, 0);
                of[mt][dt] = __builtin_amdgcn_mfma_f32_16x16x32_bf16(af1, vf1, of[mt][dt], 0, 0, 0);
            }
        }
        __syncthreads();
    }

    // l: reduce each row over its 16 lanes (once, not per iter)
#pragma unroll
    for (int mt = 0; mt < 2; ++mt)
#pragma unroll
        for (int r = 0; r < 4; ++r) {
            float l = l_acc[mt][r];
#pragma unroll
            for (int off = 1; off < 16; off <<= 1) l += __shfl_xor(l, off);
            l_acc[mt][r] = l;
        }

    // write partials (unnormalized O, fixed-M -> exactly summable)
    float* ob = opart + ((size_t)(z * 32 + bh) * NSEQ) * DHEAD;
    float* lb = lpart + (size_t)(z * 32 + bh) * NSEQ;
#pragma unroll
    for (int mt = 0; mt < 2; ++mt) {
#pragma unroll
        for (int dt = 0; dt < 4; ++dt)
#pragma unroll
            for (int r = 0; r < 4; ++r) {
                int i = i0 + wave * 32 + mt * 16 + quad * 4 + r;
                ob[(size_t)i * DHEAD + dt * 16 + l15] = of[mt][dt][r];
            }
        if (l15 == 0)
#pragma unroll
            for (int r = 0; r < 4; ++r)
                lb[i0 + wave * 32 + mt * 16 + quad * 4 + r] = l_acc[mt][r];
    }
}

// ---------------------------------------------------------------------------
// k_merge: o = (o0+o1)/(l0+l1) -> aot bf16 [b][n][h*64+d]
// ---------------------------------------------------------------------------
__global__ __launch_bounds__(256) void k_merge(
    const float* __restrict__ opart, const float* __restrict__ lpart,
    unsigned short* __restrict__ aot) {
    int t = blockIdx.x * 256 + threadIdx.x;        // 32*2048*16
    int bh = t >> 15, rem = t & 32767;
    int i = rem >> 4, d = (rem & 15) * 4;
    size_t row = (size_t)bh * NSEQ + i;
    const float* o0 = opart;
    const float* o1 = opart + (size_t)32 * NSEQ * DHEAD;
    float l = lpart[row] + lpart[(size_t)32 * NSEQ + row];
    float inv = 1.0f / fmaxf(l, 1e-30f);
    float4 a = *(const float4*)(o0 + row * DHEAD + d);
    float4 b = *(const float4*)(o1 + row * DHEAD + d);
    ushort4 o;
    o.x = f2bf((a.x + b.x) * inv); o.y = f2bf((a.y + b.y) * inv);
    o.z = f2bf((a.z + b.z) * inv); o.w = f2bf((a.w + b.w) * inv);
    int bb = bh >> 4, h = bh & 15;
    *(ushort4*)(aot + ((size_t)bb * NSEQ + i) * HDIM + h * DHEAD + d) = o;
}

// ---------------------------------------------------------------------------
// k_gemm_out: y[b][o][n] f32 = sum_c Wout[o][c]*aot[b][n][c] + bout[o]
// 64x64 tiles (512 blocks), BK=64, swizzled
// ---------------------------------------------------------------------------
__global__ __launch_bounds__(256) void k_gemm_out(
    const unsigned short* __restrict__ W, const unsigned short* __restrict__ aot,
    const float* __restrict__ bias, float* __restrict__ out) {
    constexpr int K = HDIM, N = NSEQ, M = CCH;
    __shared__ __align__(16) short lsA[64 * 64];
    __shared__ __align__(16) short lsB[64 * 64];
    const int tid = threadIdx.x, wave = tid >> 6, lane = tid & 63;
    const int l15 = lane & 15, quad = lane >> 4;
    const int n0 = blockIdx.x * 64, m0 = blockIdx.y * 64, z = blockIdx.z;
    const short* Ab = (const short*)W + (size_t)m0 * K;
    const short* Bb = (const short*)aot + ((size_t)z * N + n0) * K;
    const int wm = wave >> 1, wn = wave & 1;
    const int cswz = (((tid & 7) ^ ((tid >> 3) & 7))) * 8;
    const int sw7 = (l15 & 7);

    float4v acc[2][2];
#pragma unroll
    for (int i = 0; i < 2; ++i)
#pragma unroll
        for (int j = 0; j < 2; ++j) acc[i][j] = (float4v){0.f, 0.f, 0.f, 0.f};

    for (int k0 = 0; k0 < K; k0 += 64) {
        {
            int row = tid >> 3;          // 0..31
            cp16(Ab + (size_t)row * K + k0 + cswz, &lsA[wave * 512]);
            cp16(Ab + (size_t)(row + 32) * K + k0 + cswz, &lsA[2048 + wave * 512]);
            cp16(Bb + (size_t)row * K + k0 + cswz, &lsB[wave * 512]);
            cp16(Bb + (size_t)(row + 32) * K + k0 + cswz, &lsB[2048 + wave * 512]);
        }
        __syncthreads();
        short8 af[2][2], bfr[2][2];
#pragma unroll
        for (int t = 0; t < 2; ++t)
#pragma unroll
            for (int kk = 0; kk < 2; ++kk) {
                af[t][kk]  = *(const short8*)&lsA[(wm * 32 + t * 16 + l15) * 64 + ((kk * 4 + quad) ^ sw7) * 8];
                bfr[t][kk] = *(const short8*)&lsB[(wn * 32 + t * 16 + l15) * 64 + ((kk * 4 + quad) ^ sw7) * 8];
            }
#pragma unroll
        for (int mt = 0; mt < 2; ++mt)
#pragma unroll
            for (int nt = 0; nt < 2; ++nt) {
                acc[mt][nt] = __builtin_amdgcn_mfma_f32_16x16x32_bf16(af[mt][0], bfr[nt][0], acc[mt][nt], 0, 0, 0);
                acc[mt][nt] = __builtin_amdgcn_mfma_f32_16x16x32_bf16(af[mt][1], bfr[nt][1], acc[mt][nt], 0, 0, 0);
            }
        __syncthreads();
    }
    float* Co = out + (size_t)z * M * N;
#pragma unroll
    for (int mt = 0; mt < 2; ++mt)
#pragma unroll
        for (int nt = 0; nt < 2; ++nt) {
            int mrow = m0 + wm * 32 + mt * 16 + quad * 4;
#pragma unroll
            for (int r = 0; r < 4; ++r) {
                int mr = mrow + r;
                int nc = n0 + wn * 32 + nt * 16 + l15;
                Co[(size_t)mr * N + nc] = acc[mt][nt][r] + bias[mr];
            }
        }
}

// ---------------------------------------------------------------------------
// Launch.  Inputs resolved by element count (f32).
// ---------------------------------------------------------------------------
extern "C" void kernel_launch(void* const* d_in, const int* in_sizes, int n_in,
                              void* d_out, int out_size, void* d_ws, size_t ws_size,
                              hipStream_t stream) {
    const float* x = nullptr; const float* Wqkv = nullptr;
    const float* qs = nullptr; const float* ks = nullptr;
    const float* Wout = nullptr; const float* bout = nullptr;
    for (int i = 0; i < n_in; ++i) {
        switch (in_sizes[i]) {
            case BATCH * CCH * NSEQ: x    = (const float*)d_in[i]; break;
            case ODIM * CCH:         Wqkv = (const float*)d_in[i]; break;
            case CCH * HDIM:         Wout = (const float*)d_in[i]; break;
            case CCH:                bout = (const float*)d_in[i]; break;
            case DHEAD: if (!qs) qs = (const float*)d_in[i]; else ks = (const float*)d_in[i]; break;
            default: break;
        }
    }
    float* y = (float*)d_out;

    char* ws = (char*)d_ws;
    float*          Mbuf  = (float*)(ws + 0);
    unsigned short* Wqkvb = (unsigned short*)(ws + 4096);        // 3,145,728 B
    unsigned short* Woutb = (unsigned short*)(ws + 3149824);     // 1,048,576 B
    unsigned short* xt    = (unsigned short*)(ws + 4198400);     // 4,194,304 B
    float*          qkv   = (float*)(ws + 8392704);              // 50,331,648 B
    // opart/lpart reuse the qkv region (qkv dead after repack/vcast)
    float*          opart = (float*)(ws + 8392704);              // 33,554,432 B
    float*          lpart = (float*)(ws + 41947136);             //    524,288 B
    unsigned short* qh    = (unsigned short*)(ws + 58724352);    // 8,388,608 B
    unsigned short* kh    = (unsigned short*)(ws + 67112960);    // 8,388,608 B
    unsigned short* vb    = (unsigned short*)(ws + 75501568);    // 8,388,608 B
    unsigned short* aot   = (unsigned short*)(ws + 83890176);    // 8,388,608 B

    k_prep<<<1, 64, 0, stream>>>(qs, ks, Mbuf);
    k_convert_w<<<(ODIM * CCH + CCH * HDIM) / 4 / 256, 256, 0, stream>>>(Wqkv, Wout, Wqkvb, Woutb);
    k_transpose_x<<<dim3(NSEQ / 64, CCH / 64, BATCH), 256, 0, stream>>>(x, xt);
    k_gemm_qkv<<<dim3(NSEQ / 128, ODIM / 128, BATCH), 256, 0, stream>>>(Wqkvb, xt, qkv);
    k_repack_qk<<<dim3(NSEQ / 64, BATCH * HEADS, 2), 256, 0, stream>>>(qkv, qs, ks, qh, kh);
    k_vcast<<<dim3((BATCH * HDIM * NSEQ / 4) / 256), 256, 0, stream>>>(qkv, vb);
    k_attn<<<dim3(NSEQ / 128, BATCH * HEADS, 2), 256, 0, stream>>>(qh, kh, vb, opart, lpart, Mbuf);
    k_merge<<<dim3(BATCH * HEADS * NSEQ * (DHEAD / 4) / 256), 256, 0, stream>>>(opart, lpart, aot);
    k_gemm_out<<<dim3(NSEQ / 64, CCH / 64, BATCH), 256, 0, stream>>>(Woutb, aot, bout, y);
}

// Round 6
// 174.257 us; speedup vs baseline: 1.6555x; 1.1230x over previous
//
#include <hip/hip_runtime.h>
#include <hip/hip_bf16.h>

// ---------------------------------------------------------------------------
// Problem constants.  Inputs f32, output f32 (proven R4).
// ---------------------------------------------------------------------------
#define BATCH 2
#define CCH   512
#define NSEQ  2048
#define HEADS 16
#define DHEAD 64
#define HDIM  1024
#define ODIM  3072
#define SCALE 8.0f

typedef short short8 __attribute__((ext_vector_type(8)));
typedef float float4v __attribute__((ext_vector_type(4)));

__device__ __forceinline__ float bf2f(unsigned short b) {
    return __uint_as_float(((unsigned int)b) << 16);
}
__device__ __forceinline__ unsigned short f2bf(float f) {
    unsigned int u = __float_as_uint(f);
    return (unsigned short)((u + 0x7FFFu + ((u >> 16) & 1u)) >> 16);
}

typedef __attribute__((address_space(1))) const void* as1_cvp;
typedef __attribute__((address_space(3))) void* as3_vp;
__device__ __forceinline__ void cp16(const void* g, void* l) {
    __builtin_amdgcn_global_load_lds((as1_cvp)g, (as3_vp)l, 16, 0, 0);
}
// LDS XOR swizzle (R5, verified: SQ_LDS_BANK_CONFLICT -> 0): slot (row,chunk)
// holds global (row, chunk ^ (row&7)); staging lane fetches global chunk
// (tid&7)^((tid>>3)&7).

// ---------------------------------------------------------------------------
// k_prep: M = SCALE * max_d |qs_d*ks_d| (exact softmax bound, Cauchy-Schwarz)
// ---------------------------------------------------------------------------
__global__ __launch_bounds__(64) void k_prep(const float* __restrict__ qs,
                                             const float* __restrict__ ks,
                                             float* __restrict__ M) {
    int lane = threadIdx.x;
    float p = fabsf(qs[lane] * ks[lane]);
#pragma unroll
    for (int off = 1; off < 64; off <<= 1) p = fmaxf(p, __shfl_xor(p, off));
    if (lane == 0) *M = SCALE * p;
}

// ---------------------------------------------------------------------------
// k_convert_w: f32 -> bf16 for Wqkv then Wout
// ---------------------------------------------------------------------------
__global__ __launch_bounds__(256) void k_convert_w(
    const float* __restrict__ Wqkv, const float* __restrict__ Wout,
    unsigned short* __restrict__ Wqkvb, unsigned short* __restrict__ Woutb) {
    int i4 = (blockIdx.x * 256 + threadIdx.x) * 4;
    const float* src; unsigned short* dst; int idx;
    if (i4 < ODIM * CCH) { src = Wqkv; dst = Wqkvb; idx = i4; }
    else { src = Wout; dst = Woutb; idx = i4 - ODIM * CCH; }
    float4 v = *(const float4*)(src + idx);
    ushort4 o;
    o.x = f2bf(v.x); o.y = f2bf(v.y); o.z = f2bf(v.z); o.w = f2bf(v.w);
    *(ushort4*)(dst + idx) = o;
}

// ---------------------------------------------------------------------------
// k_transpose_x: x [b][c][n] f32 -> xt [b][n][c] bf16
// ---------------------------------------------------------------------------
__global__ __launch_bounds__(256) void k_transpose_x(
    const float* __restrict__ x, unsigned short* __restrict__ xt) {
    __shared__ unsigned short t[64][65];
    const int b = blockIdx.z, c0 = blockIdx.y * 64, n0 = blockIdx.x * 64;
    const int tr = threadIdx.x >> 6, tc = threadIdx.x & 63;
    const float* xs = x + (size_t)b * CCH * NSEQ;
    unsigned short* xd = xt + (size_t)b * NSEQ * CCH;
#pragma unroll
    for (int r = 0; r < 16; ++r) {
        int c = r * 4 + tr;
        t[c][tc] = f2bf(xs[(size_t)(c0 + c) * NSEQ + n0 + tc]);
    }
    __syncthreads();
#pragma unroll
    for (int r = 0; r < 16; ++r) {
        int n = r * 4 + tr;
        xd[(size_t)(n0 + n) * CCH + c0 + tc] = t[tc][n];
    }
}

// ---------------------------------------------------------------------------
// k_gemm_qkv: fused QKV GEMM + l2-norm/scale + head repack.
// A wave's 64 m-rows are exactly one head (m0 128-aligned, heads 64-wide),
// so full-d sums of squares live in-register: 16 local squares + shfl 16,32.
//   q/k (part<2): qh/kh[bh][n][d] bf16 ushort4 writes
//   v   (part=2): vb[bh][d][n]  bf16 scalar writes
// ---------------------------------------------------------------------------
__global__ __launch_bounds__(256) void k_gemm_qkv(
    const unsigned short* __restrict__ W, const unsigned short* __restrict__ xt,
    const float* __restrict__ qs, const float* __restrict__ ks,
    unsigned short* __restrict__ qh, unsigned short* __restrict__ kh,
    unsigned short* __restrict__ vb) {
    constexpr int K = CCH, N = NSEQ;
    __shared__ __align__(16) short lsA[128 * 64];
    __shared__ __align__(16) short lsB[128 * 64];
    const int tid = threadIdx.x, wave = tid >> 6, lane = tid & 63;
    const int l15 = lane & 15, quad = lane >> 4;
    const int n0 = blockIdx.x * 128, m0 = blockIdx.y * 128, z = blockIdx.z;
    const short* Ab = (const short*)W + (size_t)m0 * K;
    const short* Bb = (const short*)xt + ((size_t)z * N + n0) * K;
    const int wm = wave >> 1, wn = wave & 1;
    const int cswz = (((tid & 7) ^ ((tid >> 3) & 7))) * 8;
    const int sw7 = (l15 & 7);

    float4v acc[4][4];
#pragma unroll
    for (int i = 0; i < 4; ++i)
#pragma unroll
        for (int j = 0; j < 4; ++j) acc[i][j] = (float4v){0.f, 0.f, 0.f, 0.f};

    for (int k0 = 0; k0 < K; k0 += 64) {
#pragma unroll
        for (int it = 0; it < 4; ++it) {
            int row = it * 32 + (tid >> 3);
            cp16(Ab + (size_t)row * K + k0 + cswz, &lsA[it * 2048 + wave * 512]);
            cp16(Bb + (size_t)row * K + k0 + cswz, &lsB[it * 2048 + wave * 512]);
        }
        __syncthreads();
        short8 af[4][2], bfr[4][2];
#pragma unroll
        for (int t = 0; t < 4; ++t)
#pragma unroll
            for (int kk = 0; kk < 2; ++kk) {
                af[t][kk]  = *(const short8*)&lsA[(wm * 64 + t * 16 + l15) * 64 + ((kk * 4 + quad) ^ sw7) * 8];
                bfr[t][kk] = *(const short8*)&lsB[(wn * 64 + t * 16 + l15) * 64 + ((kk * 4 + quad) ^ sw7) * 8];
            }
#pragma unroll
        for (int mt = 0; mt < 4; ++mt)
#pragma unroll
            for (int nt = 0; nt < 4; ++nt) {
                acc[mt][nt] = __builtin_amdgcn_mfma_f32_16x16x32_bf16(af[mt][0], bfr[nt][0], acc[mt][nt], 0, 0, 0);
                acc[mt][nt] = __builtin_amdgcn_mfma_f32_16x16x32_bf16(af[mt][1], bfr[nt][1], acc[mt][nt], 0, 0, 0);
            }
        __syncthreads();
    }

    // ---- fused epilogue ----
    const int co   = (m0 + wm * 64) >> 6;   // chunk 0..47
    const int part = co >> 4;               // 0=q, 1=k, 2=v
    const int h    = co & 15;
    const int bh   = z * HEADS + h;

    if (part < 2) {
        float inv[4];
#pragma unroll
        for (int nt = 0; nt < 4; ++nt) {
            float ss = 0.f;
#pragma unroll
            for (int mt = 0; mt < 4; ++mt)
#pragma unroll
                for (int r = 0; r < 4; ++r) ss += acc[mt][nt][r] * acc[mt][nt][r];
            ss += __shfl_xor(ss, 16);
            ss += __shfl_xor(ss, 32);
            inv[nt] = 1.0f / fmaxf(sqrtf(ss), 1e-12f);
        }
        const float* sc = part ? ks : qs;
        unsigned short* dst = (part ? kh : qh) + (size_t)bh * NSEQ * DHEAD;
#pragma unroll
        for (int mt = 0; mt < 4; ++mt) {
            const int db = mt * 16 + quad * 4;
            float4 s4 = *(const float4*)(sc + db);
#pragma unroll
            for (int nt = 0; nt < 4; ++nt) {
                int n = n0 + wn * 64 + nt * 16 + l15;
                ushort4 o;
                o.x = f2bf(acc[mt][nt][0] * inv[nt] * s4.x);
                o.y = f2bf(acc[mt][nt][1] * inv[nt] * s4.y);
                o.z = f2bf(acc[mt][nt][2] * inv[nt] * s4.z);
                o.w = f2bf(acc[mt][nt][3] * inv[nt] * s4.w);
                *(ushort4*)(dst + (size_t)n * DHEAD + db) = o;
            }
        }
    } else {
        unsigned short* dst = vb + (size_t)bh * DHEAD * NSEQ;
#pragma unroll
        for (int mt = 0; mt < 4; ++mt)
#pragma unroll
            for (int nt = 0; nt < 4; ++nt) {
                int n = n0 + wn * 64 + nt * 16 + l15;
#pragma unroll
                for (int r = 0; r < 4; ++r) {
                    int d = mt * 16 + quad * 4 + r;
                    dst[(size_t)d * NSEQ + n] = f2bf(acc[mt][nt][r]);
                }
            }
    }
}

// ---------------------------------------------------------------------------
// k_attn: fixed-M flash attention, j-split 2, swizzled LDS, XCD-local grid.
// 1D grid 1024: all 16 i-blocks of one (bh,z) share flat%8 -> same XCD L2.
// ---------------------------------------------------------------------------
__global__ __launch_bounds__(256, 4) void k_attn(
    const unsigned short* __restrict__ qh, const unsigned short* __restrict__ kh,
    const unsigned short* __restrict__ vb,
    float* __restrict__ opart, float* __restrict__ lpart,
    const float* __restrict__ Mptr) {
    __shared__ __align__(16) short Kt[64 * 64];
    __shared__ __align__(16) short Vt[64 * 64];
    __shared__ __align__(16) short Pt[128 * 64];
    const int tid = threadIdx.x, wave = tid >> 6, lane = tid & 63;
    const int l15 = lane & 15, quad = lane >> 4, q8 = quad * 8;
    // XCD-local decode
    const int flat = blockIdx.x;
    const int xcd = flat & 7, idx = flat >> 3;
    const int g = (xcd << 3) | (idx >> 4);     // group [0,64)
    const int i0 = (idx & 15) * 128;
    const int bh = g & 31, z = g >> 5;
    const float Ms = *Mptr;
    const int cswz = (((tid & 7) ^ ((tid >> 3) & 7))) * 8;
    const int sw7 = (l15 & 7);

    short8 qf[2][2];
    const short* qb = (const short*)qh + ((size_t)bh * NSEQ + i0 + wave * 32) * DHEAD;
#pragma unroll
    for (int mt = 0; mt < 2; ++mt)
#pragma unroll
        for (int kt = 0; kt < 2; ++kt)
            qf[mt][kt] = *(const short8*)&qb[(mt * 16 + l15) * DHEAD + kt * 32 + q8];

    float4v of[2][4];
#pragma unroll
    for (int mt = 0; mt < 2; ++mt)
#pragma unroll
        for (int dt = 0; dt < 4; ++dt) of[mt][dt] = (float4v){0.f, 0.f, 0.f, 0.f};
    float l_acc[2][4];
#pragma unroll
    for (int mt = 0; mt < 2; ++mt)
#pragma unroll
        for (int r = 0; r < 4; ++r) l_acc[mt][r] = 0.f;

    const short* kbase = (const short*)kh + (size_t)bh * NSEQ * DHEAD;
    const short* vbase = (const short*)vb + (size_t)bh * DHEAD * NSEQ;

    const int jlo = z * (NSEQ / 2), jhi = jlo + NSEQ / 2;
    for (int j0 = jlo; j0 < jhi; j0 += 64) {
#pragma unroll
        for (int it = 0; it < 2; ++it) {
            int row = it * 32 + (tid >> 3);
            cp16(kbase + (size_t)(j0 + row) * DHEAD + cswz, &Kt[it * 2048 + wave * 512]);
            cp16(vbase + (size_t)row * NSEQ + j0 + cswz, &Vt[it * 2048 + wave * 512]);
        }
        __syncthreads();

        float4v s[2][4];
#pragma unroll
        for (int nt = 0; nt < 4; ++nt) {
            short8 kf0 = *(const short8*)&Kt[(nt * 16 + l15) * 64 + ((0 * 4 + quad) ^ sw7) * 8];
            short8 kf1 = *(const short8*)&Kt[(nt * 16 + l15) * 64 + ((1 * 4 + quad) ^ sw7) * 8];
#pragma unroll
            for (int mt = 0; mt < 2; ++mt) {
                float4v zz = (float4v){0.f, 0.f, 0.f, 0.f};
                zz = __builtin_amdgcn_mfma_f32_16x16x32_bf16(qf[mt][0], kf0, zz, 0, 0, 0);
                zz = __builtin_amdgcn_mfma_f32_16x16x32_bf16(qf[mt][1], kf1, zz, 0, 0, 0);
                s[mt][nt] = zz;
            }
        }

#pragma unroll
        for (int mt = 0; mt < 2; ++mt)
#pragma unroll
            for (int r = 0; r < 4; ++r) {
                int prow = wave * 32 + mt * 16 + quad * 4 + r;
                int psw = (prow & 7);
                float p0 = __expf(fmaf(s[mt][0][r], SCALE, -Ms));
                float p1 = __expf(fmaf(s[mt][1][r], SCALE, -Ms));
                float p2 = __expf(fmaf(s[mt][2][r], SCALE, -Ms));
                float p3 = __expf(fmaf(s[mt][3][r], SCALE, -Ms));
                l_acc[mt][r] += (p0 + p1) + (p2 + p3);
                Pt[prow * 64 + (((0 * 2 + (l15 >> 3)) ^ psw) * 8) + (l15 & 7)] = (short)f2bf(p0);
                Pt[prow * 64 + (((1 * 2 + (l15 >> 3)) ^ psw) * 8) + (l15 & 7)] = (short)f2bf(p1);
                Pt[prow * 64 + (((2 * 2 + (l15 >> 3)) ^ psw) * 8) + (l15 & 7)] = (short)f2bf(p2);
                Pt[prow * 64 + (((3 * 2 + (l15 >> 3)) ^ psw) * 8) + (l15 & 7)] = (short)f2bf(p3);
            }
        __syncthreads();

#pragma unroll
        for (int mt = 0; mt < 2; ++mt) {
            int arow = wave * 32 + mt * 16 + l15;
            short8 af0 = *(const short8*)&Pt[arow * 64 + ((0 * 4 + quad) ^ sw7) * 8];
            short8 af1 = *(const short8*)&Pt[arow * 64 + ((1 * 4 + quad) ^ sw7) * 8];
#pragma unroll
            for (int dt = 0; dt < 4; ++dt) {
                short8 vf0 = *(const short8*)&Vt[(dt * 16 + l15) * 64 + ((0 * 4 + quad) ^ sw7) * 8];
                short8 vf1 = *(const short8*)&Vt[(dt * 16 + l15) * 64 + ((1 * 4 + quad) ^ sw7) * 8];
                of[mt][dt] = __builtin_amdgcn_mfma_f32_16x16x32_bf16(af0, vf0, of[mt][dt], 0, 0, 0);
                of[mt][dt] = __builtin_amdgcn_mfma_f32_16x16x32_bf16(af1, vf1, of[mt][dt], 0, 0, 0);
            }
        }
        __syncthreads();
    }

#pragma unroll
    for (int mt = 0; mt < 2; ++mt)
#pragma unroll
        for (int r = 0; r < 4; ++r) {
            float l = l_acc[mt][r];
#pragma unroll
            for (int off = 1; off < 16; off <<= 1) l += __shfl_xor(l, off);
            l_acc[mt][r] = l;
        }

    float* ob = opart + ((size_t)(z * 32 + bh) * NSEQ) * DHEAD;
    float* lb = lpart + (size_t)(z * 32 + bh) * NSEQ;
#pragma unroll
    for (int mt = 0; mt < 2; ++mt) {
#pragma unroll
        for (int dt = 0; dt < 4; ++dt)
#pragma unroll
            for (int r = 0; r < 4; ++r) {
                int i = i0 + wave * 32 + mt * 16 + quad * 4 + r;
                ob[(size_t)i * DHEAD + dt * 16 + l15] = of[mt][dt][r];
            }
        if (l15 == 0)
#pragma unroll
            for (int r = 0; r < 4; ++r)
                lb[i0 + wave * 32 + mt * 16 + quad * 4 + r] = l_acc[mt][r];
    }
}

// ---------------------------------------------------------------------------
// k_merge: o = (o0+o1)/(l0+l1) -> aot bf16 [b][n][h*64+d]
// ---------------------------------------------------------------------------
__global__ __launch_bounds__(256) void k_merge(
    const float* __restrict__ opart, const float* __restrict__ lpart,
    unsigned short* __restrict__ aot) {
    int t = blockIdx.x * 256 + threadIdx.x;
    int bh = t >> 15, rem = t & 32767;
    int i = rem >> 4, d = (rem & 15) * 4;
    size_t row = (size_t)bh * NSEQ + i;
    const float* o0 = opart;
    const float* o1 = opart + (size_t)32 * NSEQ * DHEAD;
    float l = lpart[row] + lpart[(size_t)32 * NSEQ + row];
    float inv = 1.0f / fmaxf(l, 1e-30f);
    float4 a = *(const float4*)(o0 + row * DHEAD + d);
    float4 b = *(const float4*)(o1 + row * DHEAD + d);
    ushort4 o;
    o.x = f2bf((a.x + b.x) * inv); o.y = f2bf((a.y + b.y) * inv);
    o.z = f2bf((a.z + b.z) * inv); o.w = f2bf((a.w + b.w) * inv);
    int bb = bh >> 4, h = bh & 15;
    *(ushort4*)(aot + ((size_t)bb * NSEQ + i) * HDIM + h * DHEAD + d) = o;
}

// ---------------------------------------------------------------------------
// k_gemm_out: y[b][o][n] f32 = sum_c Wout[o][c]*aot[b][n][c] + bout[o]
// ---------------------------------------------------------------------------
__global__ __launch_bounds__(256) void k_gemm_out(
    const unsigned short* __restrict__ W, const unsigned short* __restrict__ aot,
    const float* __restrict__ bias, float* __restrict__ out) {
    constexpr int K = HDIM, N = NSEQ, M = CCH;
    __shared__ __align__(16) short lsA[64 * 64];
    __shared__ __align__(16) short lsB[64 * 64];
    const int tid = threadIdx.x, wave = tid >> 6, lane = tid & 63;
    const int l15 = lane & 15, quad = lane >> 4;
    const int n0 = blockIdx.x * 64, m0 = blockIdx.y * 64, z = blockIdx.z;
    const short* Ab = (const short*)W + (size_t)m0 * K;
    const short* Bb = (const short*)aot + ((size_t)z * N + n0) * K;
    const int wm = wave >> 1, wn = wave & 1;
    const int cswz = (((tid & 7) ^ ((tid >> 3) & 7))) * 8;
    const int sw7 = (l15 & 7);

    float4v acc[2][2];
#pragma unroll
    for (int i = 0; i < 2; ++i)
#pragma unroll
        for (int j = 0; j < 2; ++j) acc[i][j] = (float4v){0.f, 0.f, 0.f, 0.f};

    for (int k0 = 0; k0 < K; k0 += 64) {
        {
            int row = tid >> 3;
            cp16(Ab + (size_t)row * K + k0 + cswz, &lsA[wave * 512]);
            cp16(Ab + (size_t)(row + 32) * K + k0 + cswz, &lsA[2048 + wave * 512]);
            cp16(Bb + (size_t)row * K + k0 + cswz, &lsB[wave * 512]);
            cp16(Bb + (size_t)(row + 32) * K + k0 + cswz, &lsB[2048 + wave * 512]);
        }
        __syncthreads();
        short8 af[2][2], bfr[2][2];
#pragma unroll
        for (int t = 0; t < 2; ++t)
#pragma unroll
            for (int kk = 0; kk < 2; ++kk) {
                af[t][kk]  = *(const short8*)&lsA[(wm * 32 + t * 16 + l15) * 64 + ((kk * 4 + quad) ^ sw7) * 8];
                bfr[t][kk] = *(const short8*)&lsB[(wn * 32 + t * 16 + l15) * 64 + ((kk * 4 + quad) ^ sw7) * 8];
            }
#pragma unroll
        for (int mt = 0; mt < 2; ++mt)
#pragma unroll
            for (int nt = 0; nt < 2; ++nt) {
                acc[mt][nt] = __builtin_amdgcn_mfma_f32_16x16x32_bf16(af[mt][0], bfr[nt][0], acc[mt][nt], 0, 0, 0);
                acc[mt][nt] = __builtin_amdgcn_mfma_f32_16x16x32_bf16(af[mt][1], bfr[nt][1], acc[mt][nt], 0, 0, 0);
            }
        __syncthreads();
    }
    float* Co = out + (size_t)z * M * N;
#pragma unroll
    for (int mt = 0; mt < 2; ++mt)
#pragma unroll
        for (int nt = 0; nt < 2; ++nt) {
            int mrow = m0 + wm * 32 + mt * 16 + quad * 4;
#pragma unroll
            for (int r = 0; r < 4; ++r) {
                int mr = mrow + r;
                int nc = n0 + wn * 32 + nt * 16 + l15;
                Co[(size_t)mr * N + nc] = acc[mt][nt][r] + bias[mr];
            }
        }
}

// ---------------------------------------------------------------------------
// Launch.  Inputs resolved by element count (f32).
// ---------------------------------------------------------------------------
extern "C" void kernel_launch(void* const* d_in, const int* in_sizes, int n_in,
                              void* d_out, int out_size, void* d_ws, size_t ws_size,
                              hipStream_t stream) {
    const float* x = nullptr; const float* Wqkv = nullptr;
    const float* qs = nullptr; const float* ks = nullptr;
    const float* Wout = nullptr; const float* bout = nullptr;
    for (int i = 0; i < n_in; ++i) {
        switch (in_sizes[i]) {
            case BATCH * CCH * NSEQ: x    = (const float*)d_in[i]; break;
            case ODIM * CCH:         Wqkv = (const float*)d_in[i]; break;
            case CCH * HDIM:         Wout = (const float*)d_in[i]; break;
            case CCH:                bout = (const float*)d_in[i]; break;
            case DHEAD: if (!qs) qs = (const float*)d_in[i]; else ks = (const float*)d_in[i]; break;
            default: break;
        }
    }
    float* y = (float*)d_out;

    char* ws = (char*)d_ws;
    float*          Mbuf  = (float*)(ws + 0);
    unsigned short* Wqkvb = (unsigned short*)(ws + 4096);        // 3,145,728 B
    unsigned short* Woutb = (unsigned short*)(ws + 3149824);     // 1,048,576 B
    unsigned short* xt    = (unsigned short*)(ws + 4198400);     // 4,194,304 B
    unsigned short* qh    = (unsigned short*)(ws + 8392704);     // 8,388,608 B
    unsigned short* kh    = (unsigned short*)(ws + 16781312);    // 8,388,608 B
    unsigned short* vb    = (unsigned short*)(ws + 25169920);    // 8,388,608 B
    unsigned short* aot   = (unsigned short*)(ws + 33558528);    // 8,388,608 B
    float*          opart = (float*)(ws + 41947136);             // 33,554,432 B
    float*          lpart = (float*)(ws + 75501568);             //    524,288 B -> 76,025,856

    k_prep<<<1, 64, 0, stream>>>(qs, ks, Mbuf);
    k_convert_w<<<(ODIM * CCH + CCH * HDIM) / 4 / 256, 256, 0, stream>>>(Wqkv, Wout, Wqkvb, Woutb);
    k_transpose_x<<<dim3(NSEQ / 64, CCH / 64, BATCH), 256, 0, stream>>>(x, xt);
    k_gemm_qkv<<<dim3(NSEQ / 128, ODIM / 128, BATCH), 256, 0, stream>>>(Wqkvb, xt, qs, ks, qh, kh, vb);
    k_attn<<<dim3(1024), 256, 0, stream>>>(qh, kh, vb, opart, lpart, Mbuf);
    k_merge<<<dim3(BATCH * HEADS * NSEQ * (DHEAD / 4) / 256), 256, 0, stream>>>(opart, lpart, aot);
    k_gemm_out<<<dim3(NSEQ / 64, CCH / 64, BATCH), 256, 0, stream>>>(Woutb, aot, bout, y);
}